// Round 6
// baseline (1459.004 us; speedup 1.0000x reference)
//
#include <hip/hip_runtime.h>
#include <cstddef>
#include <cstdint>

#define NN 16384
#define FF 64
#define BM 64
#define BK 64
#define SK 2
#define KH (NN / SK)        // 8192 k per split-K slice
#define NC (KH / BK)        // 128 chunks per block

typedef __attribute__((ext_vector_type(8))) short bf16x8;
typedef __attribute__((ext_vector_type(4))) float f32x4;
typedef unsigned short ushort_t;

// truncate-split: f = hi + lo (+ ~2^-16 rel dropped); hi/lo as bf16 bit patterns
__device__ __forceinline__ void f32_split(float f, ushort_t& h, ushort_t& l) {
    unsigned u = __builtin_bit_cast(unsigned, f);
    h = (ushort_t)(u >> 16);
    float hf = __builtin_bit_cast(float, u & 0xFFFF0000u);
    float lo = f - hf;                       // exact (Sterbenz)
    l = (ushort_t)(__builtin_bit_cast(unsigned, lo) >> 16);
}

// ---------------------------------------------------------------------------
// Hop 0: Th/Tl = splitT(x) ; out = bias + x @ W0.   grid 256, 64 rows/block.
// ---------------------------------------------------------------------------
__global__ __launch_bounds__(256) void convT_init(
    const float* __restrict__ X, ushort_t* __restrict__ Th,
    ushort_t* __restrict__ Tl, const float* __restrict__ W0,
    const float* __restrict__ bias, float* __restrict__ out)
{
    __shared__ float S[64][68];
    __shared__ float W[64][64];
    const int t = threadIdx.x;
    const int rb = blockIdx.x * 64;
    {
        const int row = t >> 2;
        const int c0 = (t & 3) * 16;
        const float* src = X + (size_t)(rb + row) * FF + c0;
        *(float4*)&S[row][c0 + 0]  = *(const float4*)(src + 0);
        *(float4*)&S[row][c0 + 4]  = *(const float4*)(src + 4);
        *(float4*)&S[row][c0 + 8]  = *(const float4*)(src + 8);
        *(float4*)&S[row][c0 + 12] = *(const float4*)(src + 12);
        float4* wd = (float4*)&W[0][0];
        const float4* ws = (const float4*)W0;
#pragma unroll
        for (int j = 0; j < 4; ++j) wd[t * 4 + j] = ws[t * 4 + j];
    }
    __syncthreads();
    // split-transpose
    {
        const int cc = t >> 2;
        const int r0 = (t & 3) * 16;
        ushort_t hh[16], ll[16];
#pragma unroll
        for (int i = 0; i < 16; ++i) f32_split(S[r0 + i][cc], hh[i], ll[i]);
        unsigned wh[8], wl[8];
#pragma unroll
        for (int j = 0; j < 8; ++j) {
            wh[j] = (unsigned)hh[2 * j] | ((unsigned)hh[2 * j + 1] << 16);
            wl[j] = (unsigned)ll[2 * j] | ((unsigned)ll[2 * j + 1] << 16);
        }
        const size_t o = (size_t)cc * NN + rb + r0;
        *(uint4*)(Th + o)     = make_uint4(wh[0], wh[1], wh[2], wh[3]);
        *(uint4*)(Th + o + 8) = make_uint4(wh[4], wh[5], wh[6], wh[7]);
        *(uint4*)(Tl + o)     = make_uint4(wl[0], wl[1], wl[2], wl[3]);
        *(uint4*)(Tl + o + 8) = make_uint4(wl[4], wl[5], wl[6], wl[7]);
    }
    // out = bias + x@W0 : 2 rows x 8 cols per thread
    {
        const int row0 = (t >> 3) * 2;
        const int col0 = (t & 7) * 8;
        float acc[2][8];
        const float4 b0 = *(const float4*)(bias + col0);
        const float4 b1 = *(const float4*)(bias + col0 + 4);
#pragma unroll
        for (int r = 0; r < 2; ++r) {
            acc[r][0] = b0.x; acc[r][1] = b0.y; acc[r][2] = b0.z; acc[r][3] = b0.w;
            acc[r][4] = b1.x; acc[r][5] = b1.y; acc[r][6] = b1.z; acc[r][7] = b1.w;
        }
#pragma unroll
        for (int f = 0; f < FF; ++f) {
            const float x0 = S[row0][f];
            const float x1 = S[row0 + 1][f];
            const float4 w0 = *(const float4*)&W[f][col0];
            const float4 w1 = *(const float4*)&W[f][col0 + 4];
            acc[0][0] += x0 * w0.x; acc[0][1] += x0 * w0.y;
            acc[0][2] += x0 * w0.z; acc[0][3] += x0 * w0.w;
            acc[0][4] += x0 * w1.x; acc[0][5] += x0 * w1.y;
            acc[0][6] += x0 * w1.z; acc[0][7] += x0 * w1.w;
            acc[1][0] += x1 * w0.x; acc[1][1] += x1 * w0.y;
            acc[1][2] += x1 * w0.z; acc[1][3] += x1 * w0.w;
            acc[1][4] += x1 * w1.x; acc[1][5] += x1 * w1.y;
            acc[1][6] += x1 * w1.z; acc[1][7] += x1 * w1.w;
        }
#pragma unroll
        for (int r = 0; r < 2; ++r) {
            const size_t o = (size_t)(rb + row0 + r) * FF + col0;
            float4 v0, v1;
            v0.x = acc[r][0]; v0.y = acc[r][1]; v0.z = acc[r][2]; v0.w = acc[r][3];
            v1.x = acc[r][4]; v1.y = acc[r][5]; v1.z = acc[r][6]; v1.w = acc[r][7];
            *(float4*)(out + o) = v0;
            *(float4*)(out + o + 4) = v1;
        }
    }
}

// B register double-buffer: hi/lo x {nt, ks}
struct Bregs { bf16x8 h[2][2]; bf16x8 l[2][2]; };

// ---------------------------------------------------------------------------
// P[s] = L[:, kslice_s] @ T[kslice_s, :]  (bf16 hi/lo-split MFMA).
// grid 512: s = bx&1, m = bx>>1. 256 thr = 4 waves (2x2 of 32x32 tiles).
// A: nontemporal fp32 global -> reg (2-deep) -> split -> swizzled LDS.
// B: direct global->reg from L2-resident Th/Tl (no LDS stage, no vmcnt drain).
// ---------------------------------------------------------------------------
__global__ __launch_bounds__(256) void cheb_gemm_mfma(
    const float* __restrict__ L, const ushort_t* __restrict__ Th,
    const ushort_t* __restrict__ Tl, float* __restrict__ P)
{
    __shared__ ushort_t Ah[2][BM * BK];   // 16 KB
    __shared__ ushort_t Al[2][BM * BK];   // 16 KB

    const int tid  = threadIdx.x;
    const int lane = tid & 63;
    const int w    = tid >> 6;
    const int s    = blockIdx.x & 1;
    const int m    = blockIdx.x >> 1;
    const int row0g = m * BM;
    const size_t kbase = (size_t)s * KH;

    const int wm = w >> 1, wn = w & 1;     // wave tile (32x32) coords
    const int frow = lane & 15;            // row (A) / col (B) within 16-tile
    const int fkq  = lane >> 4;            // 0..3 -> k-offset fkq*8

    // A staging: thread owns row ar, 16 consecutive k at ak0
    const int ar   = tid >> 2;             // 0..63
    const int ak0  = (tid & 3) * 16;       // 0,16,32,48
    const int axor = (ar & 7) << 4;

    f32x4 acc[2][2];
#pragma unroll
    for (int i = 0; i < 2; ++i)
#pragma unroll
        for (int j = 0; j < 2; ++j) acc[i][j] = (f32x4)0.f;

    const float* Lbase = L + (size_t)(row0g + ar) * NN + kbase + ak0;

    const int colb = wn * 32 + frow;
    const ushort_t* bh0 = Th + (size_t)colb * NN + kbase + fkq * 8;
    const ushort_t* bh1 = bh0 + (size_t)16 * NN;
    const ushort_t* bl0 = Tl + (size_t)colb * NN + kbase + fkq * 8;
    const ushort_t* bl1 = bl0 + (size_t)16 * NN;

    f32x4 va0[4], va1[4];
    Bregs B0, B1;

#define LOADB(B, c)                                                             \
    {                                                                           \
        const size_t kc = (size_t)(c) * BK;                                     \
        B.h[0][0] = *(const bf16x8*)(bh0 + kc);                                 \
        B.h[0][1] = *(const bf16x8*)(bh0 + kc + 32);                            \
        B.h[1][0] = *(const bf16x8*)(bh1 + kc);                                 \
        B.h[1][1] = *(const bf16x8*)(bh1 + kc + 32);                            \
        B.l[0][0] = *(const bf16x8*)(bl0 + kc);                                 \
        B.l[0][1] = *(const bf16x8*)(bl0 + kc + 32);                            \
        B.l[1][0] = *(const bf16x8*)(bl1 + kc);                                 \
        B.l[1][1] = *(const bf16x8*)(bl1 + kc + 32);                            \
    }

#define LOADA(va, c)                                                            \
    {                                                                           \
        const float* g = Lbase + (size_t)(c) * BK;                              \
        va[0] = __builtin_nontemporal_load((const f32x4*)(g + 0));              \
        va[1] = __builtin_nontemporal_load((const f32x4*)(g + 4));              \
        va[2] = __builtin_nontemporal_load((const f32x4*)(g + 8));              \
        va[3] = __builtin_nontemporal_load((const f32x4*)(g + 12));             \
    }

#define WRITEA(va, slot)                                                        \
    {                                                                           \
        char* ahb = (char*)Ah[slot];                                            \
        char* alb = (char*)Al[slot];                                            \
        unsigned hw[8], lw[8];                                                  \
        _Pragma("unroll")                                                       \
        for (int j = 0; j < 4; ++j) {                                           \
            ushort_t h0, h1, h2, h3, l0, l1, l2, l3;                            \
            f32_split(va[j][0], h0, l0); f32_split(va[j][1], h1, l1);           \
            f32_split(va[j][2], h2, l2); f32_split(va[j][3], h3, l3);           \
            hw[2 * j]     = (unsigned)h0 | ((unsigned)h1 << 16);                \
            hw[2 * j + 1] = (unsigned)h2 | ((unsigned)h3 << 16);                \
            lw[2 * j]     = (unsigned)l0 | ((unsigned)l1 << 16);                \
            lw[2 * j + 1] = (unsigned)l2 | ((unsigned)l3 << 16);                \
        }                                                                       \
        const int b0 = (ar * 128 + ak0 * 2) ^ axor;                             \
        const int b1 = (ar * 128 + ak0 * 2 + 16) ^ axor;                        \
        *(uint4*)(ahb + b0) = make_uint4(hw[0], hw[1], hw[2], hw[3]);           \
        *(uint4*)(ahb + b1) = make_uint4(hw[4], hw[5], hw[6], hw[7]);           \
        *(uint4*)(alb + b0) = make_uint4(lw[0], lw[1], lw[2], lw[3]);           \
        *(uint4*)(alb + b1) = make_uint4(lw[4], lw[5], lw[6], lw[7]);           \
    }

#define COMPUTE(slot, B)                                                        \
    {                                                                           \
        const char* ahb = (const char*)Ah[slot];                                \
        const char* alb = (const char*)Al[slot];                                \
        _Pragma("unroll")                                                       \
        for (int ks = 0; ks < 2; ++ks) {                                        \
            bf16x8 Afh[2], Afl[2];                                              \
            _Pragma("unroll")                                                   \
            for (int mt = 0; mt < 2; ++mt) {                                    \
                const int row = wm * 32 + mt * 16 + frow;                       \
                const int off = (row * 128 + (ks * 32 + fkq * 8) * 2)           \
                                ^ ((row & 7) << 4);                             \
                Afh[mt] = *(const bf16x8*)(ahb + off);                          \
                Afl[mt] = *(const bf16x8*)(alb + off);                          \
            }                                                                   \
            _Pragma("unroll")                                                   \
            for (int mt = 0; mt < 2; ++mt)                                      \
                _Pragma("unroll")                                               \
                for (int nt = 0; nt < 2; ++nt) {                                \
                    acc[mt][nt] = __builtin_amdgcn_mfma_f32_16x16x32_bf16(      \
                        Afh[mt], B.h[nt][ks], acc[mt][nt], 0, 0, 0);            \
                    acc[mt][nt] = __builtin_amdgcn_mfma_f32_16x16x32_bf16(      \
                        Afh[mt], B.l[nt][ks], acc[mt][nt], 0, 0, 0);            \
                    acc[mt][nt] = __builtin_amdgcn_mfma_f32_16x16x32_bf16(      \
                        Afl[mt], B.h[nt][ks], acc[mt][nt], 0, 0, 0);            \
                }                                                               \
        }                                                                       \
    }

    // ---- prologue: chunk 0 staged; chunk 1 A-load in flight
    LOADB(B0, 0)
    LOADA(va0, 0)
    WRITEA(va0, 0)
    LOADA(va1, 1)
    __syncthreads();

#pragma unroll 1
    for (int c = 0; c < NC; c += 2) {
        // even chunk: compute slot0/B0; stage chunk c+1 into slot1
        LOADB(B1, c + 1)
        if (c + 2 < NC) LOADA(va0, c + 2)
        COMPUTE(0, B0)
        WRITEA(va1, 1)
        __syncthreads();
        // odd chunk: compute slot1/B1; stage chunk c+2 into slot0
        if (c + 2 < NC) {
            LOADB(B0, c + 2)
            if (c + 3 < NC) LOADA(va1, c + 3)
        }
        COMPUTE(1, B1)
        if (c + 2 < NC) WRITEA(va0, 0)
        __syncthreads();
    }

    // ---- write partial: C/D layout col=lane&15, row=(lane>>4)*4+r  (m89)
    float* Pp = P + (size_t)s * NN * FF;
#pragma unroll
    for (int mt = 0; mt < 2; ++mt)
#pragma unroll
        for (int nt = 0; nt < 2; ++nt) {
            const int row = row0g + wm * 32 + mt * 16 + (lane >> 4) * 4;
            const int col = wn * 32 + nt * 16 + frow;
#pragma unroll
            for (int r = 0; r < 4; ++r)
                Pp[(size_t)(row + r) * FF + col] = acc[mt][nt][r];
        }
#undef LOADB
#undef LOADA
#undef WRITEA
#undef COMPUTE
}

// ---------------------------------------------------------------------------
// Fused per-hop epilogue, 32 rows/block (grid 512):
//   t = alpha*(P0+P1) + beta*Tsub ; [Tstore]=t ; [Thn/Tln]=splitT(t) ;
//   out += t @ Wk
// ---------------------------------------------------------------------------
__global__ __launch_bounds__(256) void post_hop(
    const float* __restrict__ P0, const float* __restrict__ P1,
    const float* __restrict__ Tsub, const float* __restrict__ Wk,
    float* __restrict__ Tstore, ushort_t* __restrict__ Thn,
    ushort_t* __restrict__ Tln, float* __restrict__ out,
    float alpha, float beta)
{
    __shared__ float ST[64][33];   // ST[f][row]
    __shared__ float WK[64][64];
    const int tid = threadIdx.x;
    const int rb = blockIdx.x * 32;

    {
        float4* wd = (float4*)&WK[0][0];
        const float4* ws = (const float4*)Wk;
#pragma unroll
        for (int j = 0; j < 4; ++j) wd[tid * 4 + j] = ws[tid * 4 + j];
    }

    const int row = tid >> 3;             // 0..31
    const int c0 = (tid & 7) * 8;
    const size_t o = (size_t)(rb + row) * FF + c0;

    // phase A: t = alpha*(P0+P1) + beta*Tsub -> ST (transposed) [+ Tstore]
    {
        const float4 a0 = *(const float4*)(P0 + o);
        const float4 a1 = *(const float4*)(P0 + o + 4);
        const float4 b0 = *(const float4*)(P1 + o);
        const float4 b1 = *(const float4*)(P1 + o + 4);
        float tv[8];
        tv[0] = alpha * (a0.x + b0.x); tv[1] = alpha * (a0.y + b0.y);
        tv[2] = alpha * (a0.z + b0.z); tv[3] = alpha * (a0.w + b0.w);
        tv[4] = alpha * (a1.x + b1.x); tv[5] = alpha * (a1.y + b1.y);
        tv[6] = alpha * (a1.z + b1.z); tv[7] = alpha * (a1.w + b1.w);
        if (beta != 0.f) {
            const float4 s0 = *(const float4*)(Tsub + o);
            const float4 s1 = *(const float4*)(Tsub + o + 4);
            tv[0] += beta * s0.x; tv[1] += beta * s0.y;
            tv[2] += beta * s0.z; tv[3] += beta * s0.w;
            tv[4] += beta * s1.x; tv[5] += beta * s1.y;
            tv[6] += beta * s1.z; tv[7] += beta * s1.w;
        }
        if (Tstore) {
            float4 v0, v1;
            v0.x = tv[0]; v0.y = tv[1]; v0.z = tv[2]; v0.w = tv[3];
            v1.x = tv[4]; v1.y = tv[5]; v1.z = tv[6]; v1.w = tv[7];
            *(float4*)(Tstore + o) = v0;
            *(float4*)(Tstore + o + 4) = v1;
        }
#pragma unroll
        for (int j = 0; j < 8; ++j) ST[c0 + j][row] = tv[j];
    }
    __syncthreads();

    // phase B: split-transpose -> Thn/Tln
    if (Thn) {
        const int f = tid >> 2;           // 0..63
        const int r0 = (tid & 3) * 8;     // 0,8,16,24
        ushort_t hh[8], ll[8];
#pragma unroll
        for (int i = 0; i < 8; ++i) f32_split(ST[f][r0 + i], hh[i], ll[i]);
        unsigned wh[4], wl[4];
#pragma unroll
        for (int j = 0; j < 4; ++j) {
            wh[j] = (unsigned)hh[2 * j] | ((unsigned)hh[2 * j + 1] << 16);
            wl[j] = (unsigned)ll[2 * j] | ((unsigned)ll[2 * j + 1] << 16);
        }
        const size_t ob = (size_t)f * NN + rb + r0;
        *(uint4*)(Thn + ob) = make_uint4(wh[0], wh[1], wh[2], wh[3]);
        *(uint4*)(Tln + ob) = make_uint4(wl[0], wl[1], wl[2], wl[3]);
    }

    // phase C: out += t @ Wk
    {
        float4 a0 = *(const float4*)(out + o);
        float4 a1 = *(const float4*)(out + o + 4);
#pragma unroll
        for (int f = 0; f < FF; ++f) {
            const float sv = ST[f][row];
            const float4 w0 = *(const float4*)&WK[f][c0];
            const float4 w1 = *(const float4*)&WK[f][c0 + 4];
            a0.x += sv * w0.x; a0.y += sv * w0.y;
            a0.z += sv * w0.z; a0.w += sv * w0.w;
            a1.x += sv * w1.x; a1.y += sv * w1.y;
            a1.z += sv * w1.z; a1.w += sv * w1.w;
        }
        *(float4*)(out + o) = a0;
        *(float4*)(out + o + 4) = a1;
    }
}

extern "C" void kernel_launch(void* const* d_in, const int* in_sizes, int n_in,
                              void* d_out, int out_size, void* d_ws, size_t ws_size,
                              hipStream_t stream)
{
    const float* x    = (const float*)d_in[0];
    const float* L    = (const float*)d_in[1];
    const float* W    = (const float*)d_in[2];   // (4, 64, 64)
    const float* bias = (const float*)d_in[3];
    float* out = (float*)d_out;

    const size_t M1 = (size_t)NN * FF;           // 1,048,576 elems
    float* wsf = (float*)d_ws;
    float* T1 = wsf;                             // 4 MB
    float* P0 = wsf + M1;                        // P0,P1: 8 MB (gemm: + s*M1)
    float* P1 = P0 + M1;
    ushort_t* ThA = (ushort_t*)(wsf + 3 * M1);   // 2 MB each
    ushort_t* TlA = ThA + M1;
    ushort_t* ThB = TlA + M1;
    ushort_t* TlB = ThB + M1;

    const dim3 gc(NN / 64), bc(256);             // convT_init: 256 blocks
    const dim3 gg(SK * NN / BM), bg(256);        // gemm: 512 blocks
    const dim3 gp(NN / 32), bp(256);             // post_hop: 512 blocks

    // hop 0: ThA/TlA = splitT(x) ; out = bias + x@W0
    convT_init<<<gc, bc, 0, stream>>>(x, ThA, TlA, W + 0 * FF * FF, bias, out);
    // hop 1: T1 = L@x ; ThB/TlB = splitT(T1) ; out += T1@W1
    cheb_gemm_mfma<<<gg, bg, 0, stream>>>(L, ThA, TlA, P0);
    post_hop<<<gp, bp, 0, stream>>>(P0, P1, x, W + 1 * FF * FF,
                                    T1, ThB, TlB, out, 1.f, 0.f);
    // hop 2: T2 = 2*(L@T1) - x ; ThA/TlA = splitT(T2) ; out += T2@W2
    cheb_gemm_mfma<<<gg, bg, 0, stream>>>(L, ThB, TlB, P0);
    post_hop<<<gp, bp, 0, stream>>>(P0, P1, x, W + 2 * FF * FF,
                                    nullptr, ThA, TlA, out, 2.f, -1.f);
    // hop 3: T3 = 2*(L@T2) - T1 ; out += T3@W3
    cheb_gemm_mfma<<<gg, bg, 0, stream>>>(L, ThA, TlA, P0);
    post_hop<<<gp, bp, 0, stream>>>(P0, P1, T1, W + 3 * FF * FF,
                                    nullptr, nullptr, nullptr, out, 2.f, -1.f);
}

// Round 7
// 815.563 us; speedup vs baseline: 1.7890x; 1.7890x over previous
//
#include <hip/hip_runtime.h>
#include <cstddef>
#include <cstdint>

#define NN 16384
#define FF 64
#define BM 64
#define BK 64
#define SK 2
#define KH (NN / SK)        // 8192 k per split-K slice
#define NC (KH / BK)        // 128 chunks per block

typedef __attribute__((ext_vector_type(8))) short bf16x8;
typedef __attribute__((ext_vector_type(4))) float f32x4;
typedef unsigned short ushort_t;

// truncate-split: f = hi + lo (+ ~2^-16 rel dropped); hi/lo as bf16 bit patterns
__device__ __forceinline__ void f32_split(float f, ushort_t& h, ushort_t& l) {
    unsigned u = __builtin_bit_cast(unsigned, f);
    h = (ushort_t)(u >> 16);
    float hf = __builtin_bit_cast(float, u & 0xFFFF0000u);
    float lo = f - hf;                       // exact (Sterbenz)
    l = (ushort_t)(__builtin_bit_cast(unsigned, lo) >> 16);
}

// Pack layout (B operand, MFMA-fragment order):
//   Bp[((q*4 + cg)*64 + lane)*8 + j] = T[node = q*32 + (lane>>4)*8 + j][f = cg*16 + (lane&15)]
// GEMM lane l reads its whole fragment as ONE contiguous 16B load; lanes are
// consecutive -> 1KB coalesced per wave, straight from L2-resident 4MB pack.

// ---------------------------------------------------------------------------
// Hop 0: pack(x) ; out = bias + x @ W0.   grid 512, 32 rows/block.
// ---------------------------------------------------------------------------
__global__ __launch_bounds__(256) void convT_pack_init(
    const float* __restrict__ X, ushort_t* __restrict__ Bph,
    ushort_t* __restrict__ Bpl, const float* __restrict__ W0,
    const float* __restrict__ bias, float* __restrict__ out)
{
    __shared__ float ST[64][33];   // ST[f][row]
    __shared__ float WK[64][64];
    const int t = threadIdx.x;
    const int rb = blockIdx.x * 32;

    {
        float4* wd = (float4*)&WK[0][0];
        const float4* ws = (const float4*)W0;
#pragma unroll
        for (int j = 0; j < 4; ++j) wd[t * 4 + j] = ws[t * 4 + j];
    }
    const int row = t >> 3;            // 0..31
    const int c0 = (t & 7) * 8;
    const size_t o = (size_t)(rb + row) * FF + c0;
    {
        const float4 v0 = *(const float4*)(X + o);
        const float4 v1 = *(const float4*)(X + o + 4);
        ST[c0 + 0][row] = v0.x; ST[c0 + 1][row] = v0.y;
        ST[c0 + 2][row] = v0.z; ST[c0 + 3][row] = v0.w;
        ST[c0 + 4][row] = v1.x; ST[c0 + 5][row] = v1.y;
        ST[c0 + 6][row] = v1.z; ST[c0 + 7][row] = v1.w;
    }
    __syncthreads();

    // pack-write
    {
        const int cg = t >> 6, lane = t & 63;
        const int n0 = (lane >> 4) * 8;
        const int f = cg * 16 + (lane & 15);
        ushort_t hh[8], ll[8];
#pragma unroll
        for (int i = 0; i < 8; ++i) f32_split(ST[f][n0 + i], hh[i], ll[i]);
        unsigned wh[4], wl[4];
#pragma unroll
        for (int j = 0; j < 4; ++j) {
            wh[j] = (unsigned)hh[2 * j] | ((unsigned)hh[2 * j + 1] << 16);
            wl[j] = (unsigned)ll[2 * j] | ((unsigned)ll[2 * j + 1] << 16);
        }
        const size_t idx = (((size_t)(rb >> 5) * 4 + cg) * 64 + lane) * 8;
        *(uint4*)(Bph + idx) = make_uint4(wh[0], wh[1], wh[2], wh[3]);
        *(uint4*)(Bpl + idx) = make_uint4(wl[0], wl[1], wl[2], wl[3]);
    }

    // out = bias + x @ W0
    {
        float4 a0 = *(const float4*)(bias + c0);
        float4 a1 = *(const float4*)(bias + c0 + 4);
#pragma unroll
        for (int f = 0; f < FF; ++f) {
            const float sv = ST[f][row];
            const float4 w0 = *(const float4*)&WK[f][c0];
            const float4 w1 = *(const float4*)&WK[f][c0 + 4];
            a0.x += sv * w0.x; a0.y += sv * w0.y;
            a0.z += sv * w0.z; a0.w += sv * w0.w;
            a1.x += sv * w1.x; a1.y += sv * w1.y;
            a1.z += sv * w1.z; a1.w += sv * w1.w;
        }
        *(float4*)(out + o) = a0;
        *(float4*)(out + o + 4) = a1;
    }
}

// B register buffer: hi/lo x {nt, ks}
struct Bregs { bf16x8 h[2][2]; bf16x8 l[2][2]; };

// ---------------------------------------------------------------------------
// P[s] = L[:, kslice_s] @ T[kslice_s, :]  (bf16 hi/lo-split MFMA).
// grid 512: s = bx&1, m = bx>>1. 256 thr = 4 waves (2x2 of 32x32 tiles).
// A: fp32 global -> reg -> split -> swizzled LDS (dbuf, 1 barrier/chunk).
// B: fragment-packed direct global->reg, coalesced, prefetched 1 chunk ahead.
// ---------------------------------------------------------------------------
__global__ __launch_bounds__(256) void cheb_gemm_mfma(
    const float* __restrict__ L, const ushort_t* __restrict__ Bph,
    const ushort_t* __restrict__ Bpl, float* __restrict__ P)
{
    __shared__ ushort_t Ah[2][BM * BK];   // 16 KB
    __shared__ ushort_t Al[2][BM * BK];   // 16 KB

    const int tid  = threadIdx.x;
    const int lane = tid & 63;
    const int w    = tid >> 6;
    const int s    = blockIdx.x & 1;
    const int m    = blockIdx.x >> 1;
    const int row0g = m * BM;
    const size_t kbase = (size_t)s * KH;
    const int kb32 = s * (KH / 32);        // base k-chunk32 index

    const int wm = w >> 1, wn = w & 1;     // wave tile (32x32) coords
    const int frow = lane & 15;
    const int fkq  = lane >> 4;            // 0..3

    // A staging: thread owns row ar, 16 consecutive k at ak0
    const int ar   = tid >> 2;             // 0..63
    const int ak0  = (tid & 3) * 16;       // 0,16,32,48
    const int axor = (ar & 7) << 4;

    f32x4 acc[2][2];
#pragma unroll
    for (int i = 0; i < 2; ++i)
#pragma unroll
        for (int j = 0; j < 2; ++j) acc[i][j] = (f32x4)0.f;

    const float* Lbase = L + (size_t)(row0g + ar) * NN + kbase + ak0;
    const bf16x8* BH = (const bf16x8*)Bph;
    const bf16x8* BL = (const bf16x8*)Bpl;

    f32x4 va[4];
    Bregs B0, B1;

#define LOADB(B, c)                                                             \
    {                                                                           \
        _Pragma("unroll")                                                       \
        for (int ks = 0; ks < 2; ++ks)                                          \
            _Pragma("unroll")                                                   \
            for (int nt = 0; nt < 2; ++nt) {                                    \
                const int idx = ((kb32 + (c) * 2 + ks) * 4 + (wn * 2 + nt))     \
                                * 64 + lane;                                    \
                B.h[nt][ks] = BH[idx];                                          \
                B.l[nt][ks] = BL[idx];                                          \
            }                                                                   \
    }

#define LOADA(c)                                                                \
    {                                                                           \
        const float* g = Lbase + (size_t)(c) * BK;                              \
        va[0] = *(const f32x4*)(g + 0);                                         \
        va[1] = *(const f32x4*)(g + 4);                                         \
        va[2] = *(const f32x4*)(g + 8);                                         \
        va[3] = *(const f32x4*)(g + 12);                                        \
    }

#define WRITEA(slot)                                                            \
    {                                                                           \
        char* ahb = (char*)Ah[slot];                                            \
        char* alb = (char*)Al[slot];                                            \
        unsigned hw[8], lw[8];                                                  \
        _Pragma("unroll")                                                       \
        for (int j = 0; j < 4; ++j) {                                           \
            ushort_t h0, h1, h2, h3, l0, l1, l2, l3;                            \
            f32_split(va[j][0], h0, l0); f32_split(va[j][1], h1, l1);           \
            f32_split(va[j][2], h2, l2); f32_split(va[j][3], h3, l3);           \
            hw[2 * j]     = (unsigned)h0 | ((unsigned)h1 << 16);                \
            hw[2 * j + 1] = (unsigned)h2 | ((unsigned)h3 << 16);                \
            lw[2 * j]     = (unsigned)l0 | ((unsigned)l1 << 16);                \
            lw[2 * j + 1] = (unsigned)l2 | ((unsigned)l3 << 16);                \
        }                                                                       \
        const int b0 = (ar * 128 + ak0 * 2) ^ axor;                             \
        const int b1 = (ar * 128 + ak0 * 2 + 16) ^ axor;                        \
        *(uint4*)(ahb + b0) = make_uint4(hw[0], hw[1], hw[2], hw[3]);           \
        *(uint4*)(ahb + b1) = make_uint4(hw[4], hw[5], hw[6], hw[7]);           \
        *(uint4*)(alb + b0) = make_uint4(lw[0], lw[1], lw[2], lw[3]);           \
        *(uint4*)(alb + b1) = make_uint4(lw[4], lw[5], lw[6], lw[7]);           \
    }

#define COMPUTE(slot, B)                                                        \
    {                                                                           \
        const char* ahb = (const char*)Ah[slot];                                \
        const char* alb = (const char*)Al[slot];                                \
        _Pragma("unroll")                                                       \
        for (int ks = 0; ks < 2; ++ks) {                                        \
            bf16x8 Afh[2], Afl[2];                                              \
            _Pragma("unroll")                                                   \
            for (int mt = 0; mt < 2; ++mt) {                                    \
                const int row = wm * 32 + mt * 16 + frow;                       \
                const int off = (row * 128 + (ks * 32 + fkq * 8) * 2)           \
                                ^ ((row & 7) << 4);                             \
                Afh[mt] = *(const bf16x8*)(ahb + off);                          \
                Afl[mt] = *(const bf16x8*)(alb + off);                          \
            }                                                                   \
            _Pragma("unroll")                                                   \
            for (int mt = 0; mt < 2; ++mt)                                      \
                _Pragma("unroll")                                               \
                for (int nt = 0; nt < 2; ++nt) {                                \
                    acc[mt][nt] = __builtin_amdgcn_mfma_f32_16x16x32_bf16(      \
                        Afh[mt], B.h[nt][ks], acc[mt][nt], 0, 0, 0);            \
                    acc[mt][nt] = __builtin_amdgcn_mfma_f32_16x16x32_bf16(      \
                        Afh[mt], B.l[nt][ks], acc[mt][nt], 0, 0, 0);            \
                    acc[mt][nt] = __builtin_amdgcn_mfma_f32_16x16x32_bf16(      \
                        Afl[mt], B.h[nt][ks], acc[mt][nt], 0, 0, 0);            \
                }                                                               \
        }                                                                       \
    }

    // ---- prologue: chunk 0 staged
    LOADB(B0, 0)
    LOADA(0)
    WRITEA(0)
    __syncthreads();

#pragma unroll 1
    for (int c = 0; c < NC; c += 2) {
        // even chunk: compute slot0/B0; stage chunk c+1 -> slot1/B1
        LOADA(c + 1)
        LOADB(B1, c + 1)
        COMPUTE(0, B0)
        WRITEA(1)
        __syncthreads();
        // odd chunk: compute slot1/B1; stage chunk c+2 -> slot0/B0
        if (c + 2 < NC) {
            LOADA(c + 2)
            LOADB(B0, c + 2)
        }
        COMPUTE(1, B1)
        if (c + 2 < NC) WRITEA(0)
        __syncthreads();
    }

    // ---- write partial: C/D layout col=lane&15, row=(lane>>4)*4+r  (m89)
    float* Pp = P + (size_t)s * NN * FF;
#pragma unroll
    for (int mt = 0; mt < 2; ++mt)
#pragma unroll
        for (int nt = 0; nt < 2; ++nt) {
            const int row = row0g + wm * 32 + mt * 16 + (lane >> 4) * 4;
            const int col = wn * 32 + nt * 16 + frow;
#pragma unroll
            for (int r = 0; r < 4; ++r)
                Pp[(size_t)(row + r) * FF + col] = acc[mt][nt][r];
        }
#undef LOADB
#undef LOADA
#undef WRITEA
#undef COMPUTE
}

// ---------------------------------------------------------------------------
// Fused per-hop epilogue, 32 rows/block (grid 512):
//   t = alpha*(P0+P1) + beta*Tsub ; [Tstore]=t ; [pack -> Bph/Bpl] ;
//   out += t @ Wk
// ---------------------------------------------------------------------------
__global__ __launch_bounds__(256) void post_hop(
    const float* __restrict__ P0, const float* __restrict__ P1,
    const float* __restrict__ Tsub, const float* __restrict__ Wk,
    float* __restrict__ Tstore, ushort_t* __restrict__ Bph,
    ushort_t* __restrict__ Bpl, float* __restrict__ out,
    float alpha, float beta)
{
    __shared__ float ST[64][33];   // ST[f][row]
    __shared__ float WK[64][64];
    const int t = threadIdx.x;
    const int rb = blockIdx.x * 32;

    {
        float4* wd = (float4*)&WK[0][0];
        const float4* ws = (const float4*)Wk;
#pragma unroll
        for (int j = 0; j < 4; ++j) wd[t * 4 + j] = ws[t * 4 + j];
    }

    const int row = t >> 3;             // 0..31
    const int c0 = (t & 7) * 8;
    const size_t o = (size_t)(rb + row) * FF + c0;

    // phase A: t = alpha*(P0+P1) + beta*Tsub -> ST (transposed) [+ Tstore]
    {
        const float4 a0 = *(const float4*)(P0 + o);
        const float4 a1 = *(const float4*)(P0 + o + 4);
        const float4 b0 = *(const float4*)(P1 + o);
        const float4 b1 = *(const float4*)(P1 + o + 4);
        float tv[8];
        tv[0] = alpha * (a0.x + b0.x); tv[1] = alpha * (a0.y + b0.y);
        tv[2] = alpha * (a0.z + b0.z); tv[3] = alpha * (a0.w + b0.w);
        tv[4] = alpha * (a1.x + b1.x); tv[5] = alpha * (a1.y + b1.y);
        tv[6] = alpha * (a1.z + b1.z); tv[7] = alpha * (a1.w + b1.w);
        if (beta != 0.f) {
            const float4 s0 = *(const float4*)(Tsub + o);
            const float4 s1 = *(const float4*)(Tsub + o + 4);
            tv[0] += beta * s0.x; tv[1] += beta * s0.y;
            tv[2] += beta * s0.z; tv[3] += beta * s0.w;
            tv[4] += beta * s1.x; tv[5] += beta * s1.y;
            tv[6] += beta * s1.z; tv[7] += beta * s1.w;
        }
        if (Tstore) {
            float4 v0, v1;
            v0.x = tv[0]; v0.y = tv[1]; v0.z = tv[2]; v0.w = tv[3];
            v1.x = tv[4]; v1.y = tv[5]; v1.z = tv[6]; v1.w = tv[7];
            *(float4*)(Tstore + o) = v0;
            *(float4*)(Tstore + o + 4) = v1;
        }
#pragma unroll
        for (int j = 0; j < 8; ++j) ST[c0 + j][row] = tv[j];
    }
    __syncthreads();

    // phase B: pack-write -> Bph/Bpl (B operand for next hop's GEMM)
    if (Bph) {
        const int cg = t >> 6, lane = t & 63;
        const int n0 = (lane >> 4) * 8;
        const int f = cg * 16 + (lane & 15);
        ushort_t hh[8], ll[8];
#pragma unroll
        for (int i = 0; i < 8; ++i) f32_split(ST[f][n0 + i], hh[i], ll[i]);
        unsigned wh[4], wl[4];
#pragma unroll
        for (int j = 0; j < 4; ++j) {
            wh[j] = (unsigned)hh[2 * j] | ((unsigned)hh[2 * j + 1] << 16);
            wl[j] = (unsigned)ll[2 * j] | ((unsigned)ll[2 * j + 1] << 16);
        }
        const size_t idx = (((size_t)(rb >> 5) * 4 + cg) * 64 + lane) * 8;
        *(uint4*)(Bph + idx) = make_uint4(wh[0], wh[1], wh[2], wh[3]);
        *(uint4*)(Bpl + idx) = make_uint4(wl[0], wl[1], wl[2], wl[3]);
    }

    // phase C: out += t @ Wk
    {
        float4 a0 = *(const float4*)(out + o);
        float4 a1 = *(const float4*)(out + o + 4);
#pragma unroll
        for (int f = 0; f < FF; ++f) {
            const float sv = ST[f][row];
            const float4 w0 = *(const float4*)&WK[f][c0];
            const float4 w1 = *(const float4*)&WK[f][c0 + 4];
            a0.x += sv * w0.x; a0.y += sv * w0.y;
            a0.z += sv * w0.z; a0.w += sv * w0.w;
            a1.x += sv * w1.x; a1.y += sv * w1.y;
            a1.z += sv * w1.z; a1.w += sv * w1.w;
        }
        *(float4*)(out + o) = a0;
        *(float4*)(out + o + 4) = a1;
    }
}

extern "C" void kernel_launch(void* const* d_in, const int* in_sizes, int n_in,
                              void* d_out, int out_size, void* d_ws, size_t ws_size,
                              hipStream_t stream)
{
    const float* x    = (const float*)d_in[0];
    const float* L    = (const float*)d_in[1];
    const float* W    = (const float*)d_in[2];   // (4, 64, 64)
    const float* bias = (const float*)d_in[3];
    float* out = (float*)d_out;

    const size_t M1 = (size_t)NN * FF;           // 1,048,576 elems
    float* wsf = (float*)d_ws;
    float* T1 = wsf;                             // 4 MB
    float* P0 = wsf + M1;                        // P0,P1: 8 MB
    float* P1 = P0 + M1;
    ushort_t* BphA = (ushort_t*)(wsf + 3 * M1);  // 2 MB each pack
    ushort_t* BplA = BphA + M1;
    ushort_t* BphB = BplA + M1;
    ushort_t* BplB = BphB + M1;

    const dim3 g512(512), b256(256);

    // hop 0: packA = pack(x) ; out = bias + x@W0
    convT_pack_init<<<g512, b256, 0, stream>>>(x, BphA, BplA,
                                               W + 0 * FF * FF, bias, out);
    // hop 1: T1 = L@x ; packB = pack(T1) ; out += T1@W1
    cheb_gemm_mfma<<<g512, b256, 0, stream>>>(L, BphA, BplA, P0);
    post_hop<<<g512, b256, 0, stream>>>(P0, P1, x, W + 1 * FF * FF,
                                        T1, BphB, BplB, out, 1.f, 0.f);
    // hop 2: T2 = 2*(L@T1) - x ; packA = pack(T2) ; out += T2@W2
    cheb_gemm_mfma<<<g512, b256, 0, stream>>>(L, BphB, BplB, P0);
    post_hop<<<g512, b256, 0, stream>>>(P0, P1, x, W + 2 * FF * FF,
                                        nullptr, BphA, BplA, out, 2.f, -1.f);
    // hop 3: T3 = 2*(L@T2) - T1 ; out += T3@W3
    cheb_gemm_mfma<<<g512, b256, 0, stream>>>(L, BphA, BplA, P0);
    post_hop<<<g512, b256, 0, stream>>>(P0, P1, T1, W + 3 * FF * FF,
                                        nullptr, nullptr, nullptr, out, 2.f, -1.f);
}

// Round 8
// 725.944 us; speedup vs baseline: 2.0098x; 1.1235x over previous
//
#include <hip/hip_runtime.h>
#include <cstddef>
#include <cstdint>

#define NN 16384
#define FF 64
#define BM 64
#define BK 64
#define SK 4
#define KQ (NN / SK)        // 4096 k per split-K slice
#define NC (KQ / BK)        // 64 chunks per block

typedef __attribute__((ext_vector_type(8))) short bf16x8;
typedef __attribute__((ext_vector_type(4))) float f32x4;
typedef unsigned short ushort_t;

#define GLOBAL_AS __attribute__((address_space(1)))
#define LDS_AS    __attribute__((address_space(3)))

// truncate-split: f = hi + lo (+ ~2^-16 rel dropped); hi/lo as bf16 bit patterns
__device__ __forceinline__ void f32_split(float f, ushort_t& h, ushort_t& l) {
    unsigned u = __builtin_bit_cast(unsigned, f);
    h = (ushort_t)(u >> 16);
    float hf = __builtin_bit_cast(float, u & 0xFFFF0000u);
    float lo = f - hf;                       // exact (Sterbenz)
    l = (ushort_t)(__builtin_bit_cast(unsigned, lo) >> 16);
}

// ---------------------------------------------------------------------------
// Hop 0: Th/Tl = splitT(x) ; out = bias + x @ W0.   grid 256, 64 rows/block.
// ---------------------------------------------------------------------------
__global__ __launch_bounds__(256) void convT_init(
    const float* __restrict__ X, ushort_t* __restrict__ Th,
    ushort_t* __restrict__ Tl, const float* __restrict__ W0,
    const float* __restrict__ bias, float* __restrict__ out)
{
    __shared__ float S[64][68];
    __shared__ float W[64][64];
    const int t = threadIdx.x;
    const int rb = blockIdx.x * 64;
    {
        const int row = t >> 2;
        const int c0 = (t & 3) * 16;
        const float* src = X + (size_t)(rb + row) * FF + c0;
        *(float4*)&S[row][c0 + 0]  = *(const float4*)(src + 0);
        *(float4*)&S[row][c0 + 4]  = *(const float4*)(src + 4);
        *(float4*)&S[row][c0 + 8]  = *(const float4*)(src + 8);
        *(float4*)&S[row][c0 + 12] = *(const float4*)(src + 12);
        float4* wd = (float4*)&W[0][0];
        const float4* ws = (const float4*)W0;
#pragma unroll
        for (int j = 0; j < 4; ++j) wd[t * 4 + j] = ws[t * 4 + j];
    }
    __syncthreads();
    // split-transpose
    {
        const int cc = t >> 2;
        const int r0 = (t & 3) * 16;
        ushort_t hh[16], ll[16];
#pragma unroll
        for (int i = 0; i < 16; ++i) f32_split(S[r0 + i][cc], hh[i], ll[i]);
        unsigned wh[8], wl[8];
#pragma unroll
        for (int j = 0; j < 8; ++j) {
            wh[j] = (unsigned)hh[2 * j] | ((unsigned)hh[2 * j + 1] << 16);
            wl[j] = (unsigned)ll[2 * j] | ((unsigned)ll[2 * j + 1] << 16);
        }
        const size_t o = (size_t)cc * NN + rb + r0;
        *(uint4*)(Th + o)     = make_uint4(wh[0], wh[1], wh[2], wh[3]);
        *(uint4*)(Th + o + 8) = make_uint4(wh[4], wh[5], wh[6], wh[7]);
        *(uint4*)(Tl + o)     = make_uint4(wl[0], wl[1], wl[2], wl[3]);
        *(uint4*)(Tl + o + 8) = make_uint4(wl[4], wl[5], wl[6], wl[7]);
    }
    // out = bias + x@W0 : 2 rows x 8 cols per thread
    {
        const int row0 = (t >> 3) * 2;
        const int col0 = (t & 7) * 8;
        float acc[2][8];
        const float4 b0 = *(const float4*)(bias + col0);
        const float4 b1 = *(const float4*)(bias + col0 + 4);
#pragma unroll
        for (int r = 0; r < 2; ++r) {
            acc[r][0] = b0.x; acc[r][1] = b0.y; acc[r][2] = b0.z; acc[r][3] = b0.w;
            acc[r][4] = b1.x; acc[r][5] = b1.y; acc[r][6] = b1.z; acc[r][7] = b1.w;
        }
#pragma unroll
        for (int f = 0; f < FF; ++f) {
            const float x0 = S[row0][f];
            const float x1 = S[row0 + 1][f];
            const float4 w0 = *(const float4*)&W[f][col0];
            const float4 w1 = *(const float4*)&W[f][col0 + 4];
            acc[0][0] += x0 * w0.x; acc[0][1] += x0 * w0.y;
            acc[0][2] += x0 * w0.z; acc[0][3] += x0 * w0.w;
            acc[0][4] += x0 * w1.x; acc[0][5] += x0 * w1.y;
            acc[0][6] += x0 * w1.z; acc[0][7] += x0 * w1.w;
            acc[1][0] += x1 * w0.x; acc[1][1] += x1 * w0.y;
            acc[1][2] += x1 * w0.z; acc[1][3] += x1 * w0.w;
            acc[1][4] += x1 * w1.x; acc[1][5] += x1 * w1.y;
            acc[1][6] += x1 * w1.z; acc[1][7] += x1 * w1.w;
        }
#pragma unroll
        for (int r = 0; r < 2; ++r) {
            const size_t o = (size_t)(rb + row0 + r) * FF + col0;
            float4 v0, v1;
            v0.x = acc[r][0]; v0.y = acc[r][1]; v0.z = acc[r][2]; v0.w = acc[r][3];
            v1.x = acc[r][4]; v1.y = acc[r][5]; v1.z = acc[r][6]; v1.w = acc[r][7];
            *(float4*)(out + o) = v0;
            *(float4*)(out + o + 4) = v1;
        }
    }
}

// ---------------------------------------------------------------------------
// P[s] = L[:, kslice_s] @ T[kslice_s, :]   via bf16 hi/lo-split MFMA.
// grid SK*256: s = bx>>8, m = bx&255. 256 thr = 4 waves (2x2 of 32x32 tiles).
// A: fp32 global -> reg -> split -> swizzled LDS.  B: global_load_lds of
// [64][N] Th/Tl with pre-swizzled per-lane source.  (R4's measured-best GEMM.)
// ---------------------------------------------------------------------------
__global__ __launch_bounds__(256) void cheb_gemm_mfma(
    const float* __restrict__ L, const ushort_t* __restrict__ Th,
    const ushort_t* __restrict__ Tl, float* __restrict__ P)
{
    __shared__ ushort_t Ah[2][BM * BK];
    __shared__ ushort_t Al[2][BM * BK];
    __shared__ ushort_t Bh[2][FF * BK];
    __shared__ ushort_t Bl[2][FF * BK];

    const int tid  = threadIdx.x;
    const int lane = tid & 63;
    const int w    = tid >> 6;
    const int s    = blockIdx.x >> 8;
    const int m    = blockIdx.x & 255;
    const int row0g = m * BM;
    const int kbase = s * KQ;

    const int wm = w >> 1, wn = w & 1;      // wave tile (32x32) coords
    const int frow = lane & 15;             // row (A) / col (B) within 16-tile
    const int fk8  = (lane >> 4) * 8;       // k-offset base

    // A staging: thread covers rows arow+16p, k = akq*4..+3
    const int arow = w * 4 + (lane >> 4);
    const int akq  = lane & 15;
    const int axor = (arow & 7) << 4;

    // B staging: wave picks hi/lo tile and 4 col-octets
    const ushort_t* Tsrc = (w & 1) ? Tl : Th;
    const int boct0 = (w >> 1) * 4;

    f32x4 acc[2][2];
#pragma unroll
    for (int i = 0; i < 2; ++i)
#pragma unroll
        for (int j = 0; j < 2; ++j) acc[i][j] = (f32x4)0.f;

    float4 va[4];

    const float* Labase = L + (size_t)(row0g + arow) * NN + kbase + akq * 4;

#define ISSUE_B(c, slot)                                                        \
    {                                                                           \
        const size_t kc = (size_t)(c) * BK;                                     \
        char* bbase = (char*)((w & 1) ? Bl[slot] : Bh[slot]);                   \
        _Pragma("unroll")                                                       \
        for (int o = 0; o < 4; ++o) {                                           \
            const int oct = boct0 + o;                                          \
            const int col = oct * 8 + (lane >> 3);                              \
            const ushort_t* g = Tsrc + (size_t)col * NN + kbase + kc            \
                                + (((lane & 7) ^ (col & 7)) * 8);               \
            __builtin_amdgcn_global_load_lds((const GLOBAL_AS void*)g,          \
                (LDS_AS void*)(bbase + oct * 1024), 16, 0, 0);                  \
        }                                                                       \
    }

#define LOAD_A(c)                                                               \
    {                                                                           \
        const float* g = Labase + (size_t)(c) * BK;                             \
        va[0] = *(const float4*)(g);                                            \
        va[1] = *(const float4*)(g + (size_t)16 * NN);                          \
        va[2] = *(const float4*)(g + (size_t)32 * NN);                          \
        va[3] = *(const float4*)(g + (size_t)48 * NN);                          \
    }

#define CONV_WRITE_A(slot)                                                      \
    {                                                                           \
        char* ahb = (char*)Ah[slot];                                            \
        char* alb = (char*)Al[slot];                                            \
        _Pragma("unroll")                                                       \
        for (int p = 0; p < 4; ++p) {                                           \
            const int r = arow + p * 16;                                        \
            ushort_t h0, h1, h2, h3, l0, l1, l2, l3;                            \
            f32_split(va[p].x, h0, l0);                                         \
            f32_split(va[p].y, h1, l1);                                         \
            f32_split(va[p].z, h2, l2);                                         \
            f32_split(va[p].w, h3, l3);                                         \
            const unsigned hi01 = (unsigned)h0 | ((unsigned)h1 << 16);          \
            const unsigned hi23 = (unsigned)h2 | ((unsigned)h3 << 16);          \
            const unsigned lo01 = (unsigned)l0 | ((unsigned)l1 << 16);          \
            const unsigned lo23 = (unsigned)l2 | ((unsigned)l3 << 16);          \
            const int byte = (r * 128 + akq * 8) ^ axor;                        \
            *(uint2*)(ahb + byte) = make_uint2(hi01, hi23);                     \
            *(uint2*)(alb + byte) = make_uint2(lo01, lo23);                     \
        }                                                                       \
    }

    // ---- prologue: chunk 0 -> slot 0
    ISSUE_B(0, 0)
    LOAD_A(0)
    CONV_WRITE_A(0)
    __syncthreads();

    for (int c = 0; c < NC; ++c) {
        const int slot = c & 1;
        if (c + 1 < NC) {
            ISSUE_B(c + 1, slot ^ 1)
            LOAD_A(c + 1)
        }
        // ---- compute chunk c
        {
            const char* ahb = (const char*)Ah[slot];
            const char* alb = (const char*)Al[slot];
            const char* bhb = (const char*)Bh[slot];
            const char* blb = (const char*)Bl[slot];
#pragma unroll
            for (int ks = 0; ks < 2; ++ks) {
                const int kk = ks * 32 + fk8;
                bf16x8 Afh[2], Afl[2], Bfh[2], Bfl[2];
#pragma unroll
                for (int mt = 0; mt < 2; ++mt) {
                    const int row = wm * 32 + mt * 16 + frow;
                    const int off = (row * 128 + kk * 2) ^ ((row & 7) << 4);
                    Afh[mt] = *(const bf16x8*)(ahb + off);
                    Afl[mt] = *(const bf16x8*)(alb + off);
                }
#pragma unroll
                for (int nt = 0; nt < 2; ++nt) {
                    const int col = wn * 32 + nt * 16 + frow;
                    const int off = (col * 128 + kk * 2) ^ ((col & 7) << 4);
                    Bfh[nt] = *(const bf16x8*)(bhb + off);
                    Bfl[nt] = *(const bf16x8*)(blb + off);
                }
#pragma unroll
                for (int mt = 0; mt < 2; ++mt)
#pragma unroll
                    for (int nt = 0; nt < 2; ++nt) {
                        acc[mt][nt] = __builtin_amdgcn_mfma_f32_16x16x32_bf16(
                            Afh[mt], Bfh[nt], acc[mt][nt], 0, 0, 0);
                        acc[mt][nt] = __builtin_amdgcn_mfma_f32_16x16x32_bf16(
                            Afh[mt], Bfl[nt], acc[mt][nt], 0, 0, 0);
                        acc[mt][nt] = __builtin_amdgcn_mfma_f32_16x16x32_bf16(
                            Afl[mt], Bfh[nt], acc[mt][nt], 0, 0, 0);
                    }
            }
        }
        if (c + 1 < NC) CONV_WRITE_A(slot ^ 1)
        __syncthreads();
    }

    // ---- write partial: C/D layout col=lane&15, row=(lane>>4)*4+r  (m89)
    float* Pp = P + (size_t)s * NN * FF;
#pragma unroll
    for (int mt = 0; mt < 2; ++mt)
#pragma unroll
        for (int nt = 0; nt < 2; ++nt) {
            const int row = row0g + wm * 32 + mt * 16 + (lane >> 4) * 4;
            const int col = wn * 32 + nt * 16 + frow;
#pragma unroll
            for (int r = 0; r < 4; ++r)
                Pp[(size_t)(row + r) * FF + col] = acc[mt][nt][r];
        }
#undef ISSUE_B
#undef LOAD_A
#undef CONV_WRITE_A
}

// ---------------------------------------------------------------------------
// Fused per-hop epilogue, 32 rows/block (grid 512):
//   t = alpha*(P0+P1+P2+P3) + beta*Tsub ; [Tstore]=t ; [Thn/Tln]=splitT(t) ;
//   out += t @ Wk
// ---------------------------------------------------------------------------
__global__ __launch_bounds__(256) void post_hop(
    const float* __restrict__ P,
    const float* __restrict__ Tsub, const float* __restrict__ Wk,
    float* __restrict__ Tstore, ushort_t* __restrict__ Thn,
    ushort_t* __restrict__ Tln, float* __restrict__ out,
    float alpha, float beta)
{
    __shared__ float ST[64][33];   // ST[f][row]
    __shared__ float WK[64][64];
    const int t = threadIdx.x;
    const int rb = blockIdx.x * 32;
    const size_t M1 = (size_t)NN * FF;

    {
        float4* wd = (float4*)&WK[0][0];
        const float4* ws = (const float4*)Wk;
#pragma unroll
        for (int j = 0; j < 4; ++j) wd[t * 4 + j] = ws[t * 4 + j];
    }

    const int row = t >> 3;             // 0..31
    const int c0 = (t & 7) * 8;
    const size_t o = (size_t)(rb + row) * FF + c0;

    // phase A: t = alpha*sum(P) + beta*Tsub -> ST (transposed) [+ Tstore]
    {
        float tv[8];
#pragma unroll
        for (int half = 0; half < 2; ++half) {
            const size_t oo = o + 4 * half;
            float4 a0 = *(const float4*)(P + oo);
            const float4 a1 = *(const float4*)(P + M1 + oo);
            const float4 a2 = *(const float4*)(P + 2 * M1 + oo);
            const float4 a3 = *(const float4*)(P + 3 * M1 + oo);
            a0.x += a1.x + a2.x + a3.x; a0.y += a1.y + a2.y + a3.y;
            a0.z += a1.z + a2.z + a3.z; a0.w += a1.w + a2.w + a3.w;
            tv[4 * half + 0] = alpha * a0.x; tv[4 * half + 1] = alpha * a0.y;
            tv[4 * half + 2] = alpha * a0.z; tv[4 * half + 3] = alpha * a0.w;
        }
        if (beta != 0.f) {
            const float4 s0 = *(const float4*)(Tsub + o);
            const float4 s1 = *(const float4*)(Tsub + o + 4);
            tv[0] += beta * s0.x; tv[1] += beta * s0.y;
            tv[2] += beta * s0.z; tv[3] += beta * s0.w;
            tv[4] += beta * s1.x; tv[5] += beta * s1.y;
            tv[6] += beta * s1.z; tv[7] += beta * s1.w;
        }
        if (Tstore) {
            float4 v0, v1;
            v0.x = tv[0]; v0.y = tv[1]; v0.z = tv[2]; v0.w = tv[3];
            v1.x = tv[4]; v1.y = tv[5]; v1.z = tv[6]; v1.w = tv[7];
            *(float4*)(Tstore + o) = v0;
            *(float4*)(Tstore + o + 4) = v1;
        }
#pragma unroll
        for (int j = 0; j < 8; ++j) ST[c0 + j][row] = tv[j];
    }
    __syncthreads();

    // phase B: split-transpose -> Thn/Tln ([64][N] layout for global_load_lds)
    if (Thn) {
        const int f = t >> 2;           // 0..63
        const int r0 = (t & 3) * 8;     // 0,8,16,24
        ushort_t hh[8], ll[8];
#pragma unroll
        for (int i = 0; i < 8; ++i) f32_split(ST[f][r0 + i], hh[i], ll[i]);
        unsigned wh[4], wl[4];
#pragma unroll
        for (int j = 0; j < 4; ++j) {
            wh[j] = (unsigned)hh[2 * j] | ((unsigned)hh[2 * j + 1] << 16);
            wl[j] = (unsigned)ll[2 * j] | ((unsigned)ll[2 * j + 1] << 16);
        }
        const size_t ob = (size_t)f * NN + rb + r0;
        *(uint4*)(Thn + ob) = make_uint4(wh[0], wh[1], wh[2], wh[3]);
        *(uint4*)(Tln + ob) = make_uint4(wl[0], wl[1], wl[2], wl[3]);
    }

    // phase C: out += t @ Wk
    {
        float4 a0 = *(const float4*)(out + o);
        float4 a1 = *(const float4*)(out + o + 4);
#pragma unroll
        for (int f = 0; f < FF; ++f) {
            const float sv = ST[f][row];
            const float4 w0 = *(const float4*)&WK[f][c0];
            const float4 w1 = *(const float4*)&WK[f][c0 + 4];
            a0.x += sv * w0.x; a0.y += sv * w0.y;
            a0.z += sv * w0.z; a0.w += sv * w0.w;
            a1.x += sv * w1.x; a1.y += sv * w1.y;
            a1.z += sv * w1.z; a1.w += sv * w1.w;
        }
        *(float4*)(out + o) = a0;
        *(float4*)(out + o + 4) = a1;
    }
}

extern "C" void kernel_launch(void* const* d_in, const int* in_sizes, int n_in,
                              void* d_out, int out_size, void* d_ws, size_t ws_size,
                              hipStream_t stream)
{
    const float* x    = (const float*)d_in[0];
    const float* L    = (const float*)d_in[1];
    const float* W    = (const float*)d_in[2];   // (4, 64, 64)
    const float* bias = (const float*)d_in[3];
    float* out = (float*)d_out;

    const size_t M1 = (size_t)NN * FF;           // 1,048,576 elems
    float* wsf = (float*)d_ws;
    float* T1 = wsf;                             // 4 MB
    float* P  = wsf + M1;                        // 4 partials, 16 MB
    ushort_t* ThA = (ushort_t*)(wsf + 5 * M1);   // 2 MB each
    ushort_t* TlA = ThA + M1;
    ushort_t* ThB = TlA + M1;
    ushort_t* TlB = ThB + M1;

    const dim3 gc(NN / 64), bc(256);             // convT_init: 256 blocks
    const dim3 gg(SK * 256), bg(256);            // gemm: 1024 blocks
    const dim3 gp(NN / 32), bp(256);             // post_hop: 512 blocks

    // hop 0: ThA/TlA = splitT(x) ; out = bias + x@W0
    convT_init<<<gc, bc, 0, stream>>>(x, ThA, TlA, W + 0 * FF * FF, bias, out);
    // hop 1: T1 = L@x ; ThB/TlB = splitT(T1) ; out += T1@W1
    cheb_gemm_mfma<<<gg, bg, 0, stream>>>(L, ThA, TlA, P);
    post_hop<<<gp, bp, 0, stream>>>(P, x, W + 1 * FF * FF,
                                    T1, ThB, TlB, out, 1.f, 0.f);
    // hop 2: T2 = 2*(L@T1) - x ; ThA/TlA = splitT(T2) ; out += T2@W2
    cheb_gemm_mfma<<<gg, bg, 0, stream>>>(L, ThB, TlB, P);
    post_hop<<<gp, bp, 0, stream>>>(P, x, W + 2 * FF * FF,
                                    nullptr, ThA, TlA, out, 2.f, -1.f);
    // hop 3: T3 = 2*(L@T2) - T1 ; out += T3@W3
    cheb_gemm_mfma<<<gg, bg, 0, stream>>>(L, ThA, TlA, P);
    post_hop<<<gp, bp, 0, stream>>>(P, T1, W + 3 * FF * FF,
                                    nullptr, nullptr, nullptr, out, 2.f, -1.f);
}